// Round 5
// baseline (606.395 us; speedup 1.0000x reference)
//
#include <hip/hip_runtime.h>

#define NN 15360        // total nodes
#define NCR 11520       // compacted H1 rows: 45 per graph (q 0..14, c 30..59)
#define EPG 135         // active edges per graph, contiguous per graph
#define BATCH 256
#define D 128
#define TT 64
#define NPG 60
#define NCC 30
#define NQQ 15
#define NPROP 5
#define SKI 10

typedef __attribute__((ext_vector_type(8))) short bf16x8;
typedef __attribute__((ext_vector_type(4))) float f32x4;

__device__ __forceinline__ float bf2f(unsigned short u) {
    union { float f; unsigned int i; } t;
    t.i = ((unsigned int)u) << 16;
    return t.f;
}
__device__ __forceinline__ unsigned short f2bf(float f) {
    union { float f; unsigned int i; } t;
    t.f = f;
    unsigned int r = t.i + 0x7fffu + ((t.i >> 16) & 1u);
    return (unsigned short)(r >> 16);
}
// split v = hi + lo with |lo| <= 2^-9 |v|; residual after pair ~2^-18
__device__ __forceinline__ void split_bf(float v, unsigned short& hi, unsigned short& lo) {
    hi = f2bf(v);
    lo = f2bf(v - bf2f(hi));
}

// ---------------- node encode: h[i,d] = nf[i]*w[d]+b[d]; fp32 + split ----------------
__global__ void k_encode(const float* __restrict__ nf, const float* __restrict__ w,
                         const float* __restrict__ b, float* __restrict__ h,
                         unsigned short* __restrict__ h_hi, unsigned short* __restrict__ h_lo) {
    int idx = blockIdx.x * 256 + threadIdx.x;
    if (idx >= NN * D) return;
    int d = idx & (D - 1);
    int i = idx >> 7;
    float v = nf[i] * w[d] + b[d];
    h[idx] = v;
    unsigned short hi, lo;
    split_bf(v, hi, lo);
    h_hi[idx] = hi;
    h_lo[idx] = lo;
}

// ---------------- edge-constant precompute: uv (512 fp32) ----------------
__global__ void k_prep_uv(const float* __restrict__ ew, const float* __restrict__ eb,
                          const float* __restrict__ w1, const float* __restrict__ b1,
                          float* __restrict__ uv) {
    int t = threadIdx.x;  // 0..255
    float u = 0.f, v = 0.f;
    for (int d = 0; d < D; ++d) {
        float wv = w1[(256 + d) * 256 + t];
        u += ew[d] * wv;
        v += eb[d] * wv;
    }
    uv[t] = u;
    uv[256 + t] = v + b1[t];
}

// ---------------- weight prep: transpose to [n][k], split into hi/lo bf16 -----------
__global__ void k_prep_w(const float* __restrict__ mw1, const float* __restrict__ mw2,
                         const float* __restrict__ uw1, const float* __restrict__ uw2,
                         unsigned short* __restrict__ w1th, unsigned short* __restrict__ w1tl,
                         unsigned short* __restrict__ w2th, unsigned short* __restrict__ w2tl,
                         unsigned short* __restrict__ uw1th, unsigned short* __restrict__ uw1tl,
                         unsigned short* __restrict__ uw2th, unsigned short* __restrict__ uw2tl) {
    int idx = blockIdx.x * 256 + threadIdx.x;
    float v;
    unsigned short *ph, *pl;
    int o;
    if (idx < 65536) {  // w1t [512][128]
        int n = idx >> 7, k = idx & 127;
        v = (n < 256) ? mw1[k * 256 + n] : mw1[(128 + k) * 256 + (n - 256)];
        ph = w1th; pl = w1tl; o = idx;
    } else if (idx < 98304) {  // w2t [128][256]
        o = idx - 65536;
        int n = o >> 8, k = o & 255;
        v = mw2[k * 128 + n];
        ph = w2th; pl = w2tl;
    } else if (idx < 163840) {  // uw1t [256][256]
        o = idx - 98304;
        int n = o >> 8, k = o & 255;
        v = uw1[k * 256 + n];
        ph = uw1th; pl = uw1tl;
    } else if (idx < 196608) {  // uw2t [128][256]
        o = idx - 163840;
        int n = o >> 8, k = o & 255;
        v = uw2[k * 128 + n];
        ph = uw2th; pl = uw2tl;
    } else {
        return;
    }
    unsigned short hi, lo;
    split_bf(v, hi, lo);
    ph[o] = hi;
    pl[o] = lo;
}

// ===== dense split-MFMA GEMMs: BM=64, BN=64, BK=64, 4 waves (2x2), 3-term =====
// A in LDS (row stride 72 ushorts, conflict-free b128); B fragments straight from
// global (weights are L2-resident and shared by all blocks). 36.9KB LDS -> 4 blk/CU.

// ---- H1c(11520 x 512) fp32 = gather(h) @ w1t^T ----
__global__ __launch_bounds__(256) void k_h1c_mf(const unsigned short* __restrict__ h_hi,
                                                const unsigned short* __restrict__ h_lo,
                                                const unsigned short* __restrict__ w1th,
                                                const unsigned short* __restrict__ w1tl,
                                                float* __restrict__ H1c) {
    __shared__ unsigned short AsH[64 * 72], AsL[64 * 72];
    __shared__ int rowNode[64];
    int m0 = blockIdx.x * 64, n0 = blockIdx.y * 64;
    int tid = threadIdx.x;
    int lane = tid & 63, wid = tid >> 6;
    int wr = wid >> 1, wc = wid & 1;
    if (tid < 64) {
        int m = m0 + tid;
        int g = m / 45;
        int p = m - g * 45;
        rowNode[tid] = g * 60 + (p < 15 ? p : p + 15);
    }
    f32x4 acc[2][2] = {};
    for (int k0 = 0; k0 < 128; k0 += 64) {
        __syncthreads();
        for (int c = tid; c < 512; c += 256) {
            int row = c >> 3, kc = c & 7;
            size_t asrc = (size_t)rowNode[row] * D + k0 + kc * 8;
            *(uint4*)&AsH[row * 72 + kc * 8] = *(const uint4*)&h_hi[asrc];
            *(uint4*)&AsL[row * 72 + kc * 8] = *(const uint4*)&h_lo[asrc];
        }
        __syncthreads();
#pragma unroll
        for (int kk = 0; kk < 2; ++kk) {
            int koff = kk * 32 + (lane >> 4) * 8;
            bf16x8 ah[2], al[2], bh[2], bl[2];
#pragma unroll
            for (int i = 0; i < 2; i++) {
                int r = (wr * 32 + i * 16 + (lane & 15)) * 72 + koff;
                ah[i] = *(bf16x8*)&AsH[r];
                al[i] = *(bf16x8*)&AsL[r];
            }
#pragma unroll
            for (int j = 0; j < 2; j++) {
                size_t br = (size_t)(n0 + wc * 32 + j * 16 + (lane & 15)) * 128 + k0 + koff;
                bh[j] = *(const bf16x8*)&w1th[br];
                bl[j] = *(const bf16x8*)&w1tl[br];
            }
#pragma unroll
            for (int i = 0; i < 2; i++)
#pragma unroll
                for (int j = 0; j < 2; j++) {
                    acc[i][j] = __builtin_amdgcn_mfma_f32_16x16x32_bf16(ah[i], bh[j], acc[i][j], 0, 0, 0);
                    acc[i][j] = __builtin_amdgcn_mfma_f32_16x16x32_bf16(al[i], bh[j], acc[i][j], 0, 0, 0);
                    acc[i][j] = __builtin_amdgcn_mfma_f32_16x16x32_bf16(ah[i], bl[j], acc[i][j], 0, 0, 0);
                }
        }
    }
    int rloc = (lane >> 4) * 4;
#pragma unroll
    for (int i = 0; i < 2; i++)
#pragma unroll
        for (int j = 0; j < 2; j++) {
            int col = n0 + wc * 32 + j * 16 + (lane & 15);
#pragma unroll
            for (int r = 0; r < 2; r++) {  // unrolled pairs below for clarity
            }
#pragma unroll
            for (int r = 0; r < 4; r++) {
                int m = m0 + wr * 32 + i * 16 + rloc + r;
                H1c[(size_t)m * 512 + col] = acc[i][j][r];
            }
        }
}

// ---- U(15360 x 256) = relu([agg0+agg1 | h] @ uw1t^T + b1), split out ----
__global__ __launch_bounds__(256) void k_upd1_mf(const float* __restrict__ agg0,
                                                 const float* __restrict__ agg1,
                                                 const unsigned short* __restrict__ h_hi,
                                                 const unsigned short* __restrict__ h_lo,
                                                 const unsigned short* __restrict__ uw1th,
                                                 const unsigned short* __restrict__ uw1tl,
                                                 const float* __restrict__ b1,
                                                 unsigned short* __restrict__ Ub_hi,
                                                 unsigned short* __restrict__ Ub_lo) {
    __shared__ unsigned short AsH[64 * 72], AsL[64 * 72];
    int m0 = blockIdx.x * 64, n0 = blockIdx.y * 64;
    int tid = threadIdx.x;
    int lane = tid & 63, wid = tid >> 6;
    int wr = wid >> 1, wc = wid & 1;
    f32x4 acc[2][2] = {};
    for (int k0 = 0; k0 < 256; k0 += 64) {
        __syncthreads();
        if (k0 < 128) {
            for (int c = tid; c < 512; c += 256) {
                int row = c >> 3, kc = c & 7;
                size_t s = (size_t)(m0 + row) * D + k0 + kc * 8;
                float4 a0 = *(const float4*)&agg0[s];
                float4 a1 = *(const float4*)&agg0[s + 4];
                float4 c0 = *(const float4*)&agg1[s];
                float4 c1 = *(const float4*)&agg1[s + 4];
                float v[8] = {a0.x + c0.x, a0.y + c0.y, a0.z + c0.z, a0.w + c0.w,
                              a1.x + c1.x, a1.y + c1.y, a1.z + c1.z, a1.w + c1.w};
                unsigned int ph[4], pl[4];
#pragma unroll
                for (int t = 0; t < 4; t++) {
                    unsigned short h0, l0, h1, l1;
                    split_bf(v[2 * t], h0, l0);
                    split_bf(v[2 * t + 1], h1, l1);
                    ph[t] = (unsigned int)h0 | ((unsigned int)h1 << 16);
                    pl[t] = (unsigned int)l0 | ((unsigned int)l1 << 16);
                }
                *(uint4*)&AsH[row * 72 + kc * 8] = make_uint4(ph[0], ph[1], ph[2], ph[3]);
                *(uint4*)&AsL[row * 72 + kc * 8] = make_uint4(pl[0], pl[1], pl[2], pl[3]);
            }
        } else {
            for (int c = tid; c < 512; c += 256) {
                int row = c >> 3, kc = c & 7;
                size_t s = (size_t)(m0 + row) * D + (k0 - 128) + kc * 8;
                *(uint4*)&AsH[row * 72 + kc * 8] = *(const uint4*)&h_hi[s];
                *(uint4*)&AsL[row * 72 + kc * 8] = *(const uint4*)&h_lo[s];
            }
        }
        __syncthreads();
#pragma unroll
        for (int kk = 0; kk < 2; ++kk) {
            int koff = kk * 32 + (lane >> 4) * 8;
            bf16x8 ah[2], al[2], bh[2], bl[2];
#pragma unroll
            for (int i = 0; i < 2; i++) {
                int r = (wr * 32 + i * 16 + (lane & 15)) * 72 + koff;
                ah[i] = *(bf16x8*)&AsH[r];
                al[i] = *(bf16x8*)&AsL[r];
            }
#pragma unroll
            for (int j = 0; j < 2; j++) {
                size_t br = (size_t)(n0 + wc * 32 + j * 16 + (lane & 15)) * 256 + k0 + koff;
                bh[j] = *(const bf16x8*)&uw1th[br];
                bl[j] = *(const bf16x8*)&uw1tl[br];
            }
#pragma unroll
            for (int i = 0; i < 2; i++)
#pragma unroll
                for (int j = 0; j < 2; j++) {
                    acc[i][j] = __builtin_amdgcn_mfma_f32_16x16x32_bf16(ah[i], bh[j], acc[i][j], 0, 0, 0);
                    acc[i][j] = __builtin_amdgcn_mfma_f32_16x16x32_bf16(al[i], bh[j], acc[i][j], 0, 0, 0);
                    acc[i][j] = __builtin_amdgcn_mfma_f32_16x16x32_bf16(ah[i], bl[j], acc[i][j], 0, 0, 0);
                }
        }
    }
    int rloc = (lane >> 4) * 4;
#pragma unroll
    for (int i = 0; i < 2; i++)
#pragma unroll
        for (int j = 0; j < 2; j++) {
            int col = n0 + wc * 32 + j * 16 + (lane & 15);
            float bias = b1[col];
#pragma unroll
            for (int r = 0; r < 4; r++) {
                int m = m0 + wr * 32 + i * 16 + rloc + r;
                float v = fmaxf(acc[i][j][r] + bias, 0.f);
                unsigned short hi, lo;
                split_bf(v, hi, lo);
                Ub_hi[(size_t)m * 256 + col] = hi;
                Ub_lo[(size_t)m * 256 + col] = lo;
            }
        }
}

// ---- h(15360x128) += U @ uw2t^T + b2 ; fp32 residual + re-split h ----
__global__ __launch_bounds__(256) void k_upd2_mf(const unsigned short* __restrict__ Ub_hi,
                                                 const unsigned short* __restrict__ Ub_lo,
                                                 const unsigned short* __restrict__ uw2th,
                                                 const unsigned short* __restrict__ uw2tl,
                                                 const float* __restrict__ b2,
                                                 float* __restrict__ h,
                                                 unsigned short* __restrict__ h_hi,
                                                 unsigned short* __restrict__ h_lo) {
    __shared__ unsigned short AsH[64 * 72], AsL[64 * 72];
    int m0 = blockIdx.x * 64, n0 = blockIdx.y * 64;
    int tid = threadIdx.x;
    int lane = tid & 63, wid = tid >> 6;
    int wr = wid >> 1, wc = wid & 1;
    f32x4 acc[2][2] = {};
    for (int k0 = 0; k0 < 256; k0 += 64) {
        __syncthreads();
        for (int c = tid; c < 512; c += 256) {
            int row = c >> 3, kc = c & 7;
            size_t s = (size_t)(m0 + row) * 256 + k0 + kc * 8;
            *(uint4*)&AsH[row * 72 + kc * 8] = *(const uint4*)&Ub_hi[s];
            *(uint4*)&AsL[row * 72 + kc * 8] = *(const uint4*)&Ub_lo[s];
        }
        __syncthreads();
#pragma unroll
        for (int kk = 0; kk < 2; ++kk) {
            int koff = kk * 32 + (lane >> 4) * 8;
            bf16x8 ah[2], al[2], bh[2], bl[2];
#pragma unroll
            for (int i = 0; i < 2; i++) {
                int r = (wr * 32 + i * 16 + (lane & 15)) * 72 + koff;
                ah[i] = *(bf16x8*)&AsH[r];
                al[i] = *(bf16x8*)&AsL[r];
            }
#pragma unroll
            for (int j = 0; j < 2; j++) {
                size_t br = (size_t)(n0 + wc * 32 + j * 16 + (lane & 15)) * 256 + k0 + koff;
                bh[j] = *(const bf16x8*)&uw2th[br];
                bl[j] = *(const bf16x8*)&uw2tl[br];
            }
#pragma unroll
            for (int i = 0; i < 2; i++)
#pragma unroll
                for (int j = 0; j < 2; j++) {
                    acc[i][j] = __builtin_amdgcn_mfma_f32_16x16x32_bf16(ah[i], bh[j], acc[i][j], 0, 0, 0);
                    acc[i][j] = __builtin_amdgcn_mfma_f32_16x16x32_bf16(al[i], bh[j], acc[i][j], 0, 0, 0);
                    acc[i][j] = __builtin_amdgcn_mfma_f32_16x16x32_bf16(ah[i], bl[j], acc[i][j], 0, 0, 0);
                }
        }
    }
    int rloc = (lane >> 4) * 4;
#pragma unroll
    for (int i = 0; i < 2; i++)
#pragma unroll
        for (int j = 0; j < 2; j++) {
            int col = n0 + wc * 32 + j * 16 + (lane & 15);
            float bias = b2[col];
#pragma unroll
            for (int r = 0; r < 4; r++) {
                int m = m0 + wr * 32 + i * 16 + rloc + r;
                size_t o = (size_t)m * D + col;
                float v = h[o] + acc[i][j][r] + bias;
                h[o] = v;
                unsigned short hi, lo;
                split_bf(v, hi, lo);
                h_hi[o] = hi;
                h_lo[o] = lo;
            }
        }
}

// ===== per-graph edge pass, split-MFMA, M-split: block=(graph, half) =====
// half 0: edges 0..71, half 1: edges 72..134. M=80 (padded), N=128, K=256.
// Writes fp32 partial agg0/agg1 (no atomics, both fully written).
__global__ __launch_bounds__(256) void k_edge_mf(const float* __restrict__ H1c,
                                                 const float* __restrict__ uv,
                                                 const int* __restrict__ fr,
                                                 const int* __restrict__ to,
                                                 const float* __restrict__ ef,
                                                 const float* __restrict__ mfi,
                                                 const unsigned short* __restrict__ w2th,
                                                 const unsigned short* __restrict__ w2tl,
                                                 const float* __restrict__ b2,
                                                 float* __restrict__ agg0,
                                                 float* __restrict__ agg1) {
    __shared__ unsigned short AsH[80 * 40], AsL[80 * 40];  // stride 80B (5x16B)
    __shared__ float aggl[NPG][128];
    __shared__ float uvl[512];
    __shared__ int cfs[80], ctc[80], ctl[80];
    __shared__ float efs[80], ms_[80];
    int g = blockIdx.x;
    int half = blockIdx.y;
    int tid = threadIdx.x;
    int lane = tid & 63, wid = tid >> 6;
    int cnt = half ? (EPG - 72) : 72;  // 63 or 72
    int ebase = g * EPG + half * 72;
    if (tid < 80) {
        if (tid < cnt) {
            int f = fr[ebase + tid] - g * 60;
            int t = to[ebase + tid] - g * 60;
            cfs[tid] = g * 45 + (f < 15 ? f : f - 15);
            ctc[tid] = g * 45 + (t < 15 ? t : t - 15);
            ctl[tid] = t;
            efs[tid] = ef[ebase + tid];
            ms_[tid] = mfi[ebase + tid];
        } else {
            cfs[tid] = g * 45; ctc[tid] = g * 45; ctl[tid] = 0;
            efs[tid] = 0.f; ms_[tid] = 0.f;
        }
    }
    for (int i = tid; i < 512; i += 256) uvl[i] = uv[i];
    for (int i = tid; i < NPG * 128; i += 256) (&aggl[0][0])[i] = 0.f;
    f32x4 acc[5][2] = {};
    for (int ks = 0; ks < 8; ++ks) {
        __syncthreads();
        // A: Z = relu(H1[from][k] + H1[to][256+k] + ef*u + v) fp32, split to hi/lo
        for (int c = tid; c < 320; c += 256) {
            int row = c >> 2, kc = c & 3;
            int k = ks * 32 + kc * 8;
            const float* pf = H1c + (size_t)cfs[row] * 512 + k;
            const float* pt = H1c + (size_t)ctc[row] * 512 + 256 + k;
            float e_ = efs[row];
            float4 f0 = *(const float4*)pf, f1 = *(const float4*)(pf + 4);
            float4 t0 = *(const float4*)pt, t1 = *(const float4*)(pt + 4);
            float zf[8] = {f0.x + t0.x, f0.y + t0.y, f0.z + t0.z, f0.w + t0.w,
                           f1.x + t1.x, f1.y + t1.y, f1.z + t1.z, f1.w + t1.w};
            unsigned int ph[4], pl[4];
#pragma unroll
            for (int t = 0; t < 4; t++) {
                float z0 = fmaxf(zf[2 * t]     + e_ * uvl[k + 2 * t]     + uvl[256 + k + 2 * t], 0.f);
                float z1 = fmaxf(zf[2 * t + 1] + e_ * uvl[k + 2 * t + 1] + uvl[256 + k + 2 * t + 1], 0.f);
                unsigned short h0, l0, h1, l1;
                split_bf(z0, h0, l0);
                split_bf(z1, h1, l1);
                ph[t] = (unsigned int)h0 | ((unsigned int)h1 << 16);
                pl[t] = (unsigned int)l0 | ((unsigned int)l1 << 16);
            }
            *(uint4*)&AsH[row * 40 + kc * 8] = make_uint4(ph[0], ph[1], ph[2], ph[3]);
            *(uint4*)&AsL[row * 40 + kc * 8] = make_uint4(pl[0], pl[1], pl[2], pl[3]);
        }
        __syncthreads();
        int koff = (lane >> 4) * 8;
        bf16x8 bh[2], bl[2];
#pragma unroll
        for (int j = 0; j < 2; j++) {
            size_t br = (size_t)(wid * 32 + j * 16 + (lane & 15)) * 256 + ks * 32 + koff;
            bh[j] = *(const bf16x8*)&w2th[br];
            bl[j] = *(const bf16x8*)&w2tl[br];
        }
#pragma unroll
        for (int i = 0; i < 5; i++) {
            int r = (i * 16 + (lane & 15)) * 40 + koff;
            bf16x8 ah = *(bf16x8*)&AsH[r];
            bf16x8 al = *(bf16x8*)&AsL[r];
#pragma unroll
            for (int j = 0; j < 2; j++) {
                acc[i][j] = __builtin_amdgcn_mfma_f32_16x16x32_bf16(ah, bh[j], acc[i][j], 0, 0, 0);
                acc[i][j] = __builtin_amdgcn_mfma_f32_16x16x32_bf16(al, bh[j], acc[i][j], 0, 0, 0);
                acc[i][j] = __builtin_amdgcn_mfma_f32_16x16x32_bf16(ah, bl[j], acc[i][j], 0, 0, 0);
            }
        }
    }
    __syncthreads();
    int rloc = (lane >> 4) * 4;
#pragma unroll
    for (int i = 0; i < 5; i++)
#pragma unroll
        for (int j = 0; j < 2; j++) {
            int col = wid * 32 + j * 16 + (lane & 15);
            float bias = b2[col];
#pragma unroll
            for (int r = 0; r < 4; r++) {
                int e = i * 16 + rloc + r;
                if (e < cnt) {
                    float val = (acc[i][j][r] + bias) * ms_[e];
                    atomicAdd(&aggl[ctl[e]][col], val);
                }
            }
        }
    __syncthreads();
    float* dst = half ? agg1 : agg0;
    for (int idx = tid; idx < NPG * 128; idx += 256) {
        int r = idx >> 7, c = idx & 127;
        dst[(size_t)(g * NPG + r) * D + c] = aggl[r][c];
    }
}

// ---------------- final transform: t = relu(h@ft1+b1)@ft2+b2, q-mask (fp32) --------
__global__ __launch_bounds__(64) void k_transform(const float* __restrict__ h,
                                                  const float* __restrict__ w1,
                                                  const float* __restrict__ b1,
                                                  const float* __restrict__ w2,
                                                  const float* __restrict__ b2,
                                                  float* __restrict__ tout) {
    __shared__ float row[D];
    __shared__ float hid[TT];
    int i = blockIdx.x;
    int j = threadIdx.x;  // 0..63
    row[j] = h[(size_t)i * D + j];
    row[j + 64] = h[(size_t)i * D + j + 64];
    __syncthreads();
    float s = b1[j];
    for (int k = 0; k < D; k++) s += row[k] * w1[k * TT + j];
    hid[j] = fmaxf(s, 0.f);
    __syncthreads();
    float o = b2[j];
    for (int k = 0; k < TT; k++) o += hid[k] * w2[k * TT + j];
    int p = i % NPG;
    if (p >= NQQ && p < NCC) o = 0.f;
    tout[(size_t)i * TT + j] = o;
}

// ---------------- per-graph Sinkhorn + scoring (fp32) ----------------
__global__ __launch_bounds__(256) void k_sinkhorn(const float* __restrict__ h,
                                                  const float* __restrict__ tall,
                                                  float* __restrict__ out) {
    __shared__ float la[NCC * NCC];
    __shared__ float tqs[NCC][TT];
    __shared__ float tcs[NCC][TT];
    __shared__ float ce[NCC][D];
    __shared__ float lse[NCC];
    __shared__ float red[256];
    int g = blockIdx.x;
    int tid = threadIdx.x;
    for (int idx = tid; idx < NCC * TT; idx += 256) {
        int r = idx / TT, k = idx % TT;
        tqs[r][k] = tall[(size_t)(g * NPG + r) * TT + k];
        tcs[r][k] = tall[(size_t)(g * NPG + NCC + r) * TT + k];
    }
    for (int idx = tid; idx < NCC * D; idx += 256) {
        int c = idx / D, d = idx % D;
        ce[c][d] = h[(size_t)(g * NPG + NCC + c) * D + d];
    }
    __syncthreads();
    for (int e = tid; e < NCC * NCC; e += 256) {
        int q = e / NCC, c = e % NCC;
        float s = 0.f;
        for (int k = 0; k < TT; k++) s += tqs[q][k] * tcs[c][k];
        la[e] = s * 10.0f;
    }
    __syncthreads();
    for (int it = 0; it < SKI; ++it) {
        if (tid < NCC) {
            float m = -INFINITY;
            for (int c = 0; c < NCC; c++) m = fmaxf(m, la[tid * NCC + c]);
            float s = 0.f;
            for (int c = 0; c < NCC; c++) s += expf(la[tid * NCC + c] - m);
            lse[tid] = m + logf(s);
        }
        __syncthreads();
        for (int e = tid; e < NCC * NCC; e += 256) la[e] -= lse[e / NCC];
        __syncthreads();
        if (tid < NCC) {
            float m = -INFINITY;
            for (int q = 0; q < NCC; q++) m = fmaxf(m, la[q * NCC + tid]);
            float s = 0.f;
            for (int q = 0; q < NCC; q++) s += expf(la[q * NCC + tid] - m);
            lse[tid] = m + logf(s);
        }
        __syncthreads();
        for (int e = tid; e < NCC * NCC; e += 256) la[e] -= lse[e % NCC];
        __syncthreads();
    }
    for (int e = tid; e < NCC * NCC; e += 256) la[e] = expf(la[e]);
    __syncthreads();
    float part = 0.f;
    for (int idx = tid; idx < NCC * D; idx += 256) {
        int q = idx / D, d = idx % D;
        float mv = 0.f;
        for (int c = 0; c < NCC; c++) mv += la[q * NCC + c] * ce[c][d];
        float qe = h[(size_t)(g * NPG + q) * D + d];
        part += fmaxf(qe - mv, 0.f);
    }
    red[tid] = part;
    __syncthreads();
    for (int s2 = 128; s2 > 0; s2 >>= 1) {
        if (tid < s2) red[tid] += red[tid + s2];
        __syncthreads();
    }
    if (tid == 0) out[g] = -red[0];
}

extern "C" void kernel_launch(void* const* d_in, const int* in_sizes, int n_in,
                              void* d_out, int out_size, void* d_ws, size_t ws_size,
                              hipStream_t stream) {
    const float* nf  = (const float*)d_in[0];
    const float* ef  = (const float*)d_in[1];
    const float* mfi = (const float*)d_in[2];
    const float* enw = (const float*)d_in[3];
    const float* enb = (const float*)d_in[4];
    const float* eew = (const float*)d_in[5];
    const float* eeb = (const float*)d_in[6];
    const float* mw1 = (const float*)d_in[7];
    const float* mb1 = (const float*)d_in[8];
    const float* mw2 = (const float*)d_in[9];
    const float* mb2 = (const float*)d_in[10];
    const float* uw1 = (const float*)d_in[11];
    const float* ub1 = (const float*)d_in[12];
    const float* uw2 = (const float*)d_in[13];
    const float* ub2 = (const float*)d_in[14];
    const float* f1w = (const float*)d_in[15];
    const float* f1b = (const float*)d_in[16];
    const float* f2w = (const float*)d_in[17];
    const float* f2b = (const float*)d_in[18];
    const int* fr = (const int*)d_in[19];
    const int* to = (const int*)d_in[20];
    float* out = (float*)d_out;

    // workspace layout
    char* base = (char*)d_ws;
    size_t off = 0;
    float* h = (float*)(base + off);                 off += (size_t)NN * D * 4;
    unsigned short* h_hi = (unsigned short*)(base + off); off += (size_t)NN * D * 2;
    unsigned short* h_lo = (unsigned short*)(base + off); off += (size_t)NN * D * 2;
    // H1c fp32 region; Ub hi/lo pair aliases it (phase-disjoint within an iteration)
    float* H1c = (float*)(base + off);
    unsigned short* Ub_hi = (unsigned short*)H1c;
    unsigned short* Ub_lo = Ub_hi + (size_t)NN * 256;
    off += (size_t)NCR * 512 * 4;
    float* agg0 = (float*)(base + off); off += (size_t)NN * D * 4;
    float* agg1 = (float*)(base + off); off += (size_t)NN * D * 4;
    unsigned short* w1th = (unsigned short*)(base + off); off += 65536 * 2;
    unsigned short* w1tl = (unsigned short*)(base + off); off += 65536 * 2;
    unsigned short* w2th = (unsigned short*)(base + off); off += 32768 * 2;
    unsigned short* w2tl = (unsigned short*)(base + off); off += 32768 * 2;
    unsigned short* uw1th = (unsigned short*)(base + off); off += 65536 * 2;
    unsigned short* uw1tl = (unsigned short*)(base + off); off += 65536 * 2;
    unsigned short* uw2th = (unsigned short*)(base + off); off += 32768 * 2;
    unsigned short* uw2tl = (unsigned short*)(base + off); off += 32768 * 2;
    float* uv = (float*)(base + off); off += 512 * 4;
    float* tall = (float*)agg0;  // alias: transform runs after the loop, agg dead

    k_encode<<<(NN * D + 255) / 256, 256, 0, stream>>>(nf, enw, enb, h, h_hi, h_lo);
    k_prep_uv<<<1, 256, 0, stream>>>(eew, eeb, mw1, mb1, uv);
    k_prep_w<<<768, 256, 0, stream>>>(mw1, mw2, uw1, uw2, w1th, w1tl, w2th, w2tl,
                                      uw1th, uw1tl, uw2th, uw2tl);

    for (int it = 0; it < NPROP; ++it) {
        k_h1c_mf<<<dim3(NCR / 64, 8), 256, 0, stream>>>(h_hi, h_lo, w1th, w1tl, H1c);
        k_edge_mf<<<dim3(BATCH, 2), 256, 0, stream>>>(H1c, uv, fr, to, ef, mfi,
                                                      w2th, w2tl, mb2, agg0, agg1);
        k_upd1_mf<<<dim3(NN / 64, 4), 256, 0, stream>>>(agg0, agg1, h_hi, h_lo,
                                                        uw1th, uw1tl, ub1, Ub_hi, Ub_lo);
        k_upd2_mf<<<dim3(NN / 64, 2), 256, 0, stream>>>(Ub_hi, Ub_lo, uw2th, uw2tl,
                                                        ub2, h, h_hi, h_lo);
    }

    k_transform<<<NN, 64, 0, stream>>>(h, f1w, f1b, f2w, f2b, tall);
    k_sinkhorn<<<BATCH, 256, 0, stream>>>(h, tall, out);
}